// Round 9
// baseline (923.023 us; speedup 1.0000x reference)
//
#include <hip/hip_runtime.h>
#include <hip/hip_bf16.h>

#define TPB 256

// ---------------------------------------------------------------------------
// Problem constants (from reference): H=4 heads, C=64, EMB=128, G=64 groups.
// N, E taken from in_sizes at launch.
// ---------------------------------------------------------------------------

__global__ void gather_emb_k(const int* __restrict__ x, const float* __restrict__ emb,
                             float* __restrict__ h0, int n) {
  int idx = blockIdx.x * TPB + threadIdx.x;
  if (idx >= n * 128) return;
  int node = idx >> 7, k = idx & 127;
  h0[idx] = emb[x[node * 2] * 128 + k];
}

__global__ void edge_hist_k(const int* __restrict__ ei, int* __restrict__ deg, int E, int n) {
  int e = blockIdx.x * TPB + threadIdx.x;
  if (e >= E + n) return;
  int dst = (e < E) ? ei[E + e] : (e - E);
  atomicAdd(&deg[dst], 1);
}

__global__ void scan_block_k(const int* __restrict__ deg, int* __restrict__ row_ptr,
                             int* __restrict__ bsum, int n) {
  __shared__ int buf[TPB];
  int t = threadIdx.x, base = blockIdx.x * TPB;
  int v = (base + t < n) ? deg[base + t] : 0;
  buf[t] = v;
  __syncthreads();
  for (int off = 1; off < TPB; off <<= 1) {
    int xv = (t >= off) ? buf[t - off] : 0;
    __syncthreads();
    buf[t] += xv;
    __syncthreads();
  }
  if (base + t < n) row_ptr[base + t + 1] = buf[t];
  if (t == TPB - 1) bsum[blockIdx.x] = buf[t];
}

__global__ void scan_bsum_k(int* __restrict__ bsum, int B) {
  __shared__ int buf[TPB];
  int t = threadIdx.x;
  int v = (t < B) ? bsum[t] : 0;
  buf[t] = v;
  __syncthreads();
  for (int off = 1; off < TPB; off <<= 1) {
    int xv = (t >= off) ? buf[t - off] : 0;
    __syncthreads();
    buf[t] += xv;
    __syncthreads();
  }
  if (t < B) bsum[t] = buf[t] - v;  // exclusive block offsets
}

__global__ void scan_add_k(int* __restrict__ row_ptr, const int* __restrict__ bsum, int n) {
  int idx = blockIdx.x * TPB + threadIdx.x;
  if (idx == 0) row_ptr[0] = 0;
  if (idx < n) row_ptr[idx + 1] += bsum[idx >> 8];
}

__global__ void edge_scatter_k(const int* __restrict__ ei, const int* __restrict__ row_ptr,
                               int* __restrict__ cursor, int* __restrict__ csr_src,
                               int E, int n) {
  int e = blockIdx.x * TPB + threadIdx.x;
  if (e >= E + n) return;
  int src, dst;
  if (e < E) { src = ei[e]; dst = ei[E + e]; }
  else       { src = e - E; dst = e - E; }
  int pos = atomicAdd(&cursor[dst], 1);
  csr_src[row_ptr[dst] + pos] = src;
}

// hW[n][256] = h[n][K] @ W[K][256].  16 nodes x 256 cols per block.
// h loads are block-uniform (scalar path); W loads coalesced across threads.
template <int K>
__global__ __launch_bounds__(TPB) void gemm_hw_k(const float* __restrict__ h,
                                                 const float* __restrict__ W,
                                                 float* __restrict__ hW, int n) {
  int t = threadIdx.x;
  int n0 = blockIdx.x * 16;
  float acc[16];
#pragma unroll
  for (int i = 0; i < 16; i++) acc[i] = 0.f;
  const float* hb = h + (size_t)n0 * K;
  for (int k0 = 0; k0 < K; k0 += 8) {
    float wv[8];
#pragma unroll
    for (int kk = 0; kk < 8; kk++) wv[kk] = W[(k0 + kk) * 256 + t];
#pragma unroll
    for (int i = 0; i < 16; i++) {
#pragma unroll
      for (int kk = 0; kk < 8; kk++)
        acc[i] = fmaf(hb[i * K + k0 + kk], wv[kk], acc[i]);
    }
  }
  float* outp = hW + (size_t)n0 * 256 + t;
#pragma unroll
  for (int i = 0; i < 16; i++)
    if (n0 + i < n) outp[i * 256] = acc[i];
}

// a_src[n][h] = sum_c hW[n][h*64+c]*as[h][c];  a_dst likewise.
__global__ void attn_coef_k(const float* __restrict__ hW, const float* __restrict__ as,
                            const float* __restrict__ ad, float* __restrict__ a_srcv,
                            float* __restrict__ a_dstv, int n) {
  int idx = blockIdx.x * TPB + threadIdx.x;
  if (idx >= n * 4) return;
  int node = idx >> 2, hh = idx & 3;
  const float* row = hW + (size_t)node * 256 + hh * 64;
  const float* asr = as + hh * 64;
  const float* adr = ad + hh * 64;
  float s = 0.f, d = 0.f;
#pragma unroll 8
  for (int c = 0; c < 64; c++) {
    float v = row[c];
    s = fmaf(v, asr[c], s);
    d = fmaf(v, adr[c], d);
  }
  a_srcv[idx] = s;
  a_dstv[idx] = d;
}

// One block per dst node.  Wave w (of 4) handles edges beg+w, beg+w+4, ...
// Lane l covers cols [4l, 4l+3] (head = l>>4) with a float4 gather of hW.
// Branchless online softmax, single fast exp per edge:
//   diff = e - m;  mn = max(m,e);  t = __expf(-|diff|)
//   diff>0 ? (scale=t, p=1) : (scale=1, p=t)
__global__ __launch_bounds__(TPB) void gat_agg_k(
    const float* __restrict__ hW, const float* __restrict__ a_srcv,
    const float* __restrict__ a_dstv, const int* __restrict__ row_ptr,
    const int* __restrict__ csr_src, const float* __restrict__ bias,
    float* __restrict__ h_out, int n) {
  int node = blockIdx.x;
  int t = threadIdx.x;
  int w = t >> 6;         // wave 0..3
  int l = t & 63;         // lane 0..63
  int hh = l >> 4;        // head 0..3 (16 lanes/head, 4 cols/lane)
  int beg = row_ptr[node], end = row_ptr[node + 1];
  float ad = a_dstv[node * 4 + hh];

  float m = -1e30f, ssum = 0.f;
  float ax = 0.f, ay = 0.f, az = 0.f, aw = 0.f;

  for (int k = beg + w; k < end; k += 4) {
    int s = csr_src[k];
    float e = a_srcv[s * 4 + hh] + ad;
    e = (e >= 0.f) ? e : 0.2f * e;           // leaky relu
    float diff = e - m;                       // +huge on first edge
    float ex = __expf(-fabsf(diff));          // exp(-|e-m|), one transcendental
    bool nm = diff > 0.f;
    float scale = nm ? ex : 1.f;
    float p     = nm ? 1.f : ex;
    m = nm ? e : m;
    ssum = fmaf(ssum, scale, p);
    const float4 hv = *reinterpret_cast<const float4*>(hW + (size_t)s * 256 + l * 4);
    ax = fmaf(ax, scale, p * hv.x);
    ay = fmaf(ay, scale, p * hv.y);
    az = fmaf(az, scale, p * hv.z);
    aw = fmaf(aw, scale, p * hv.w);
  }

  // cross-wave combine (waves hold partials at different running maxima)
  __shared__ float m_sh[4][4];   // [wave][head]
  __shared__ float s_sh[4][4];
  __shared__ float red[4][256];  // [wave][col]
  if ((l & 15) == 0) m_sh[w][hh] = m;
  __syncthreads();
  float mt = fmaxf(fmaxf(m_sh[0][hh], m_sh[1][hh]), fmaxf(m_sh[2][hh], m_sh[3][hh]));
  float sc = __expf(m - mt);     // 0 for waves with no edges (m=-1e30)
  if ((l & 15) == 0) s_sh[w][hh] = ssum * sc;
  float* rw = &red[w][l * 4];
  rw[0] = ax * sc; rw[1] = ay * sc; rw[2] = az * sc; rw[3] = aw * sc;
  __syncthreads();

  if (t < 64) {
    float o = 0.f;
#pragma unroll
    for (int h = 0; h < 4; ++h) {
      int cc = h * 64 + t;
      float v = red[0][cc] + red[1][cc] + red[2][cc] + red[3][cc];
      float st = s_sh[0][h] + s_sh[1][h] + s_sh[2][h] + s_sh[3][h];
      o += v / (st + 1e-16f);
    }
    o = o * 0.25f + bias[t];
    o = (o > 0.f) ? o : (expf(o) - 1.f);     // ELU (precise, matches reference)
    h_out[node * 64 + t] = o;
  }
}

// ---- atomic-free pooling (batch is sorted => groups are contiguous) ----
// Boundary detection with plain stores: each gstart entry written by exactly
// one thread.  gstart[g] = first node index with batch >= g.
__global__ void group_bounds_k(const int* __restrict__ batch, int* __restrict__ gstart,
                               int G_, int n) {
  int i = blockIdx.x * TPB + threadIdx.x;
  if (i >= n) return;
  if (i == 0) {
    int b0 = batch[0];
    for (int g = 0; g <= b0; ++g) gstart[g] = 0;
  } else {
    int bp = batch[i - 1], bc = batch[i];
    for (int g = bp + 1; g <= bc; ++g) gstart[g] = i;
  }
  if (i == n - 1) {
    int bl = batch[n - 1];
    for (int g = bl + 1; g <= G_; ++g) gstart[g] = n;
  }
}

// One block per group: deterministic coalesced mean over contiguous node range.
__global__ void pool_group_k(const float* __restrict__ h, const int* __restrict__ gstart,
                             float* __restrict__ pooled) {
  int g = blockIdx.x, t = threadIdx.x;
  int c = t & 63, sub = t >> 6;  // 4 partial accumulators per column
  int beg = gstart[g], end = gstart[g + 1];
  float s = 0.f;
  for (int i = beg + sub; i < end; i += 4) s += h[(size_t)i * 64 + c];
  __shared__ float red[4][64];
  red[sub][c] = s;
  __syncthreads();
  if (t < 64) {
    float v = red[0][t] + red[1][t] + red[2][t] + red[3][t];
    float cn = fmaxf((float)(end - beg), 1.f);
    pooled[g * 64 + t] = v / cn;
  }
}

__global__ void readout_k(const float* __restrict__ pooled,
                          const float* __restrict__ mW1, const float* __restrict__ mb1,
                          const float* __restrict__ mW2, const float* __restrict__ mb2,
                          const float* __restrict__ rW, const float* __restrict__ rb,
                          float* __restrict__ out) {
  int g = blockIdx.x, t = threadIdx.x;
  __shared__ float pm[64], r1[64], r2[64];
  pm[t] = pooled[g * 64 + t];
  __syncthreads();
  float a = mb1[t];
  for (int c = 0; c < 64; c++) a = fmaf(pm[c], mW1[c * 64 + t], a);
  a = (a > 0.f) ? a : (expf(a) - 1.f);
  r1[t] = a;
  __syncthreads();
  float b = mb2[t];
  for (int c = 0; c < 64; c++) b = fmaf(r1[c], mW2[c * 64 + t], b);
  r2[t] = b;
  __syncthreads();
  if (t == 0) {
    float o = rb[0];
    for (int c = 0; c < 64; c++) o = fmaf(r2[c], rW[c], o);
    out[g] = o;
  }
}

extern "C" void kernel_launch(void* const* d_in, const int* in_sizes, int n_in,
                              void* d_out, int out_size, void* d_ws, size_t ws_size,
                              hipStream_t stream) {
  const int* x     = (const int*)d_in[0];
  const int* ei    = (const int*)d_in[1];
  const int* batch = (const int*)d_in[2];
  const float* emb = (const float*)d_in[3];
  const float* W0  = (const float*)d_in[4];
  const float* as0 = (const float*)d_in[5];
  const float* ad0 = (const float*)d_in[6];
  const float* b0  = (const float*)d_in[7];
  const float* W1  = (const float*)d_in[8];
  const float* as1 = (const float*)d_in[9];
  const float* ad1 = (const float*)d_in[10];
  const float* b1  = (const float*)d_in[11];
  const float* W2  = (const float*)d_in[12];
  const float* as2 = (const float*)d_in[13];
  const float* ad2 = (const float*)d_in[14];
  const float* b2  = (const float*)d_in[15];
  const float* mW1 = (const float*)d_in[16];
  const float* mb1 = (const float*)d_in[17];
  const float* mW2 = (const float*)d_in[18];
  const float* mb2 = (const float*)d_in[19];
  const float* rW  = (const float*)d_in[20];
  const float* rb  = (const float*)d_in[21];
  float* out = (float*)d_out;

  const int N = in_sizes[2];       // 50000
  const int E = in_sizes[1] / 2;   // 800000
  const int TOT = E + N;           // edges incl self loops
  const int G = out_size;          // 64

  // workspace carve-up
  char* p = (char*)d_ws;
  auto alloc = [&](size_t bytes) {
    void* r = (void*)p;
    p += (bytes + 255) & ~(size_t)255;
    return r;
  };
  float* hA      = (float*)alloc((size_t)(N + 16) * 128 * 4);
  float* hWbuf   = (float*)alloc((size_t)(N + 16) * 256 * 4);
  float* hB      = (float*)alloc((size_t)(N + 16) * 64 * 4);
  float* a_srcv  = (float*)alloc((size_t)N * 4 * 4);
  float* a_dstv  = (float*)alloc((size_t)N * 4 * 4);
  int*   deg     = (int*)alloc((size_t)N * 4);
  int*   row_ptr = (int*)alloc((size_t)(N + 1) * 4);
  int*   bsum    = (int*)alloc(256 * 4);
  int*   csr     = (int*)alloc((size_t)TOT * 4);
  float* pooled  = (float*)alloc((size_t)G * 64 * 4);
  int*   gstart  = (int*)alloc((size_t)(G + 1) * 4);

  int gTOT = (TOT + TPB - 1) / TPB;
  int gN   = (N + TPB - 1) / TPB;
  int B    = gN;  // scan blocks (<=256 for N<=65536)

  // ---- CSR build (per call; ws is re-poisoned each launch) ----
  hipMemsetAsync(deg, 0, (size_t)N * 4, stream);
  edge_hist_k<<<gTOT, TPB, 0, stream>>>(ei, deg, E, N);
  scan_block_k<<<B, TPB, 0, stream>>>(deg, row_ptr, bsum, N);
  scan_bsum_k<<<1, TPB, 0, stream>>>(bsum, B);
  scan_add_k<<<gN, TPB, 0, stream>>>(row_ptr, bsum, N);
  hipMemsetAsync(deg, 0, (size_t)N * 4, stream);  // reuse as cursor
  edge_scatter_k<<<gTOT, TPB, 0, stream>>>(ei, row_ptr, deg, csr, E, N);

  // ---- group bounds for pooling (batch sorted => contiguous groups) ----
  group_bounds_k<<<gN, TPB, 0, stream>>>(batch, gstart, G, N);

  // ---- embedding gather ----
  gather_emb_k<<<(N * 128 + TPB - 1) / TPB, TPB, 0, stream>>>(x, emb, hA, N);

  int gGemm = (N + 15) / 16;
  int gCoef = (N * 4 + TPB - 1) / TPB;

  // ---- layer 0 ----
  gemm_hw_k<128><<<gGemm, TPB, 0, stream>>>(hA, W0, hWbuf, N);
  attn_coef_k<<<gCoef, TPB, 0, stream>>>(hWbuf, as0, ad0, a_srcv, a_dstv, N);
  gat_agg_k<<<N, TPB, 0, stream>>>(hWbuf, a_srcv, a_dstv, row_ptr, csr, b0, hB, N);
  // ---- layer 1 ----
  gemm_hw_k<64><<<gGemm, TPB, 0, stream>>>(hB, W1, hWbuf, N);
  attn_coef_k<<<gCoef, TPB, 0, stream>>>(hWbuf, as1, ad1, a_srcv, a_dstv, N);
  gat_agg_k<<<N, TPB, 0, stream>>>(hWbuf, a_srcv, a_dstv, row_ptr, csr, b1, hA, N);
  // ---- layer 2 ----
  gemm_hw_k<64><<<gGemm, TPB, 0, stream>>>(hA, W2, hWbuf, N);
  attn_coef_k<<<gCoef, TPB, 0, stream>>>(hWbuf, as2, ad2, a_srcv, a_dstv, N);
  gat_agg_k<<<N, TPB, 0, stream>>>(hWbuf, a_srcv, a_dstv, row_ptr, csr, b2, hB, N);

  // ---- pooling + readout (atomic-free) ----
  pool_group_k<<<G, TPB, 0, stream>>>(hB, gstart, pooled);
  readout_k<<<G, 64, 0, stream>>>(pooled, mW1, mb1, mW2, mb2, rW, rb, out);
}

// Round 11
// 897.054 us; speedup vs baseline: 1.0289x; 1.0289x over previous
//
#include <hip/hip_runtime.h>
#include <hip/hip_bf16.h>

#define TPB 256
#define CHUNK 8

// ---------------------------------------------------------------------------
// Problem constants (from reference): H=4 heads, C=64, EMB=128, G=64 groups.
// N, E taken from in_sizes at launch.
// ---------------------------------------------------------------------------

__global__ void gather_emb_k(const int* __restrict__ x, const float* __restrict__ emb,
                             float* __restrict__ h0, int n) {
  int idx = blockIdx.x * TPB + threadIdx.x;
  if (idx >= n * 128) return;
  int node = idx >> 7, k = idx & 127;
  h0[idx] = emb[x[node * 2] * 128 + k];
}

__global__ void edge_hist_k(const int* __restrict__ ei, int* __restrict__ deg, int E, int n) {
  int e = blockIdx.x * TPB + threadIdx.x;
  if (e >= E + n) return;
  int dst = (e < E) ? ei[E + e] : (e - E);
  atomicAdd(&deg[dst], 1);
}

__global__ void scan_block_k(const int* __restrict__ deg, int* __restrict__ row_ptr,
                             int* __restrict__ bsum, int n) {
  __shared__ int buf[TPB];
  int t = threadIdx.x, base = blockIdx.x * TPB;
  int v = (base + t < n) ? deg[base + t] : 0;
  buf[t] = v;
  __syncthreads();
  for (int off = 1; off < TPB; off <<= 1) {
    int xv = (t >= off) ? buf[t - off] : 0;
    __syncthreads();
    buf[t] += xv;
    __syncthreads();
  }
  if (base + t < n) row_ptr[base + t + 1] = buf[t];
  if (t == TPB - 1) bsum[blockIdx.x] = buf[t];
}

__global__ void scan_bsum_k(int* __restrict__ bsum, int B) {
  __shared__ int buf[TPB];
  int t = threadIdx.x;
  int v = (t < B) ? bsum[t] : 0;
  buf[t] = v;
  __syncthreads();
  for (int off = 1; off < TPB; off <<= 1) {
    int xv = (t >= off) ? buf[t - off] : 0;
    __syncthreads();
    buf[t] += xv;
    __syncthreads();
  }
  if (t < B) bsum[t] = buf[t] - v;  // exclusive block offsets
}

__global__ void scan_add_k(int* __restrict__ row_ptr, const int* __restrict__ bsum, int n) {
  int idx = blockIdx.x * TPB + threadIdx.x;
  if (idx == 0) row_ptr[0] = 0;
  if (idx < n) row_ptr[idx + 1] += bsum[idx >> 8];
}

__global__ void edge_scatter_k(const int* __restrict__ ei, const int* __restrict__ row_ptr,
                               int* __restrict__ cursor, int* __restrict__ csr_src,
                               int E, int n) {
  int e = blockIdx.x * TPB + threadIdx.x;
  if (e >= E + n) return;
  int src, dst;
  if (e < E) { src = ei[e]; dst = ei[E + e]; }
  else       { src = e - E; dst = e - E; }
  int pos = atomicAdd(&cursor[dst], 1);
  csr_src[row_ptr[dst] + pos] = src;
}

// hW[n][256] = h[n][K] @ W[K][256].  16 nodes x 256 cols per block.
// h loads are block-uniform (scalar path); W loads coalesced across threads.
template <int K>
__global__ __launch_bounds__(TPB) void gemm_hw_k(const float* __restrict__ h,
                                                 const float* __restrict__ W,
                                                 float* __restrict__ hW, int n) {
  int t = threadIdx.x;
  int n0 = blockIdx.x * 16;
  float acc[16];
#pragma unroll
  for (int i = 0; i < 16; i++) acc[i] = 0.f;
  const float* hb = h + (size_t)n0 * K;
  for (int k0 = 0; k0 < K; k0 += 8) {
    float wv[8];
#pragma unroll
    for (int kk = 0; kk < 8; kk++) wv[kk] = W[(k0 + kk) * 256 + t];
#pragma unroll
    for (int i = 0; i < 16; i++) {
#pragma unroll
      for (int kk = 0; kk < 8; kk++)
        acc[i] = fmaf(hb[i * K + k0 + kk], wv[kk], acc[i]);
    }
  }
  float* outp = hW + (size_t)n0 * 256 + t;
#pragma unroll
  for (int i = 0; i < 16; i++)
    if (n0 + i < n) outp[i * 256] = acc[i];
}

// a_src[n][h] = sum_c hW[n][h*64+c]*as[h][c];  a_dst likewise.
__global__ void attn_coef_k(const float* __restrict__ hW, const float* __restrict__ as,
                            const float* __restrict__ ad, float* __restrict__ a_srcv,
                            float* __restrict__ a_dstv, int n) {
  int idx = blockIdx.x * TPB + threadIdx.x;
  if (idx >= n * 4) return;
  int node = idx >> 2, hh = idx & 3;
  const float* row = hW + (size_t)node * 256 + hh * 64;
  const float* asr = as + hh * 64;
  const float* adr = ad + hh * 64;
  float s = 0.f, d = 0.f;
#pragma unroll 8
  for (int c = 0; c < 64; c++) {
    float v = row[c];
    s = fmaf(v, asr[c], s);
    d = fmaf(v, adr[c], d);
  }
  a_srcv[idx] = s;
  a_dstv[idx] = d;
}

// One block per dst node.  Wave w (of 4) handles edges beg+w, beg+w+4, ...
// Lane l covers cols [4l, 4l+3] (head = l>>4) with a float4 gather of hW.
// CHUNK-deep software pipeline: stage all csr indices, then all gathers
// (16 independent loads in flight), then the serial online-softmax chain.
// Validity (k < end) is wave-uniform => branch skips loads, no divergence.
__global__ __launch_bounds__(TPB) void gat_agg_k(
    const float* __restrict__ hW, const float* __restrict__ a_srcv,
    const float* __restrict__ a_dstv, const int* __restrict__ row_ptr,
    const int* __restrict__ csr_src, const float* __restrict__ bias,
    float* __restrict__ h_out, int n) {
  int node = blockIdx.x;
  int t = threadIdx.x;
  int w = t >> 6;         // wave 0..3
  int l = t & 63;         // lane 0..63
  int hh = l >> 4;        // head 0..3 (16 lanes/head, 4 cols/lane)
  int beg = row_ptr[node], end = row_ptr[node + 1];
  float ad = a_dstv[node * 4 + hh];

  float m = -1e30f, ssum = 0.f;
  float ax = 0.f, ay = 0.f, az = 0.f, aw = 0.f;

  for (int base = beg + w; base < end; base += 4 * CHUNK) {
    int   ss[CHUNK];
    float ee[CHUNK];
    float4 hv[CHUNK];
    // stage 1: indices (independent loads, same cache lines)
#pragma unroll
    for (int j = 0; j < CHUNK; j++) {
      int k = base + j * 4;                 // wave-uniform validity
      ss[j] = (k < end) ? csr_src[k] : -1;
    }
    // stage 2: issue all gathers (a_srcv + hW rows) -- 2*CHUNK loads in flight
#pragma unroll
    for (int j = 0; j < CHUNK; j++) {
      if (ss[j] >= 0) {
        float e = a_srcv[ss[j] * 4 + hh] + ad;
        ee[j] = (e >= 0.f) ? e : 0.2f * e;  // leaky relu
        hv[j] = *reinterpret_cast<const float4*>(hW + (size_t)ss[j] * 256 + l * 4);
      } else {
        ee[j] = -1e30f;                      // sentinel: p -> 0 below
        hv[j] = make_float4(0.f, 0.f, 0.f, 0.f);
      }
    }
    // stage 3: serial online-softmax chain (one fast exp per edge)
#pragma unroll
    for (int j = 0; j < CHUNK; j++) {
      float e = ee[j];
      float diff = e - m;                    // +huge on first edge
      float ex = __expf(-fabsf(diff));       // exp(-|e-m|)
      bool nm = diff > 0.f;
      float scale = nm ? ex : 1.f;
      float p     = nm ? 1.f : ex;
      m = nm ? e : m;
      ssum = fmaf(ssum, scale, p);
      ax = fmaf(ax, scale, p * hv[j].x);
      ay = fmaf(ay, scale, p * hv[j].y);
      az = fmaf(az, scale, p * hv[j].z);
      aw = fmaf(aw, scale, p * hv[j].w);
    }
  }

  // cross-wave combine (waves hold partials at different running maxima)
  __shared__ float m_sh[4][4];   // [wave][head]
  __shared__ float s_sh[4][4];
  __shared__ float red[4][256];  // [wave][col]
  if ((l & 15) == 0) m_sh[w][hh] = m;
  __syncthreads();
  float mt = fmaxf(fmaxf(m_sh[0][hh], m_sh[1][hh]), fmaxf(m_sh[2][hh], m_sh[3][hh]));
  float sc = __expf(m - mt);     // 0 for waves with no (valid) edges
  if ((l & 15) == 0) s_sh[w][hh] = ssum * sc;
  float* rw = &red[w][l * 4];
  rw[0] = ax * sc; rw[1] = ay * sc; rw[2] = az * sc; rw[3] = aw * sc;
  __syncthreads();

  if (t < 64) {
    float o = 0.f;
#pragma unroll
    for (int h = 0; h < 4; ++h) {
      int cc = h * 64 + t;
      float v = red[0][cc] + red[1][cc] + red[2][cc] + red[3][cc];
      float st = s_sh[0][h] + s_sh[1][h] + s_sh[2][h] + s_sh[3][h];
      o += v / (st + 1e-16f);
    }
    o = o * 0.25f + bias[t];
    o = (o > 0.f) ? o : (expf(o) - 1.f);     // ELU (precise, matches reference)
    h_out[node * 64 + t] = o;
  }
}

// ---- atomic-free pooling (batch is sorted => groups are contiguous) ----
// Boundary detection with plain stores: each gstart entry written by exactly
// one thread.  gstart[g] = first node index with batch >= g.
__global__ void group_bounds_k(const int* __restrict__ batch, int* __restrict__ gstart,
                               int G_, int n) {
  int i = blockIdx.x * TPB + threadIdx.x;
  if (i >= n) return;
  if (i == 0) {
    int b0 = batch[0];
    for (int g = 0; g <= b0; ++g) gstart[g] = 0;
  } else {
    int bp = batch[i - 1], bc = batch[i];
    for (int g = bp + 1; g <= bc; ++g) gstart[g] = i;
  }
  if (i == n - 1) {
    int bl = batch[n - 1];
    for (int g = bl + 1; g <= G_; ++g) gstart[g] = n;
  }
}

// One block per group: deterministic coalesced mean over contiguous node range.
__global__ void pool_group_k(const float* __restrict__ h, const int* __restrict__ gstart,
                             float* __restrict__ pooled) {
  int g = blockIdx.x, t = threadIdx.x;
  int c = t & 63, sub = t >> 6;  // 4 partial accumulators per column
  int beg = gstart[g], end = gstart[g + 1];
  float s = 0.f;
  for (int i = beg + sub; i < end; i += 4) s += h[(size_t)i * 64 + c];
  __shared__ float red[4][64];
  red[sub][c] = s;
  __syncthreads();
  if (t < 64) {
    float v = red[0][t] + red[1][t] + red[2][t] + red[3][t];
    float cn = fmaxf((float)(end - beg), 1.f);
    pooled[g * 64 + t] = v / cn;
  }
}

__global__ void readout_k(const float* __restrict__ pooled,
                          const float* __restrict__ mW1, const float* __restrict__ mb1,
                          const float* __restrict__ mW2, const float* __restrict__ mb2,
                          const float* __restrict__ rW, const float* __restrict__ rb,
                          float* __restrict__ out) {
  int g = blockIdx.x, t = threadIdx.x;
  __shared__ float pm[64], r1[64], r2[64];
  pm[t] = pooled[g * 64 + t];
  __syncthreads();
  float a = mb1[t];
  for (int c = 0; c < 64; c++) a = fmaf(pm[c], mW1[c * 64 + t], a);
  a = (a > 0.f) ? a : (expf(a) - 1.f);
  r1[t] = a;
  __syncthreads();
  float b = mb2[t];
  for (int c = 0; c < 64; c++) b = fmaf(r1[c], mW2[c * 64 + t], b);
  r2[t] = b;
  __syncthreads();
  if (t == 0) {
    float o = rb[0];
    for (int c = 0; c < 64; c++) o = fmaf(r2[c], rW[c], o);
    out[g] = o;
  }
}

extern "C" void kernel_launch(void* const* d_in, const int* in_sizes, int n_in,
                              void* d_out, int out_size, void* d_ws, size_t ws_size,
                              hipStream_t stream) {
  const int* x     = (const int*)d_in[0];
  const int* ei    = (const int*)d_in[1];
  const int* batch = (const int*)d_in[2];
  const float* emb = (const float*)d_in[3];
  const float* W0  = (const float*)d_in[4];
  const float* as0 = (const float*)d_in[5];
  const float* ad0 = (const float*)d_in[6];
  const float* b0  = (const float*)d_in[7];
  const float* W1  = (const float*)d_in[8];
  const float* as1 = (const float*)d_in[9];
  const float* ad1 = (const float*)d_in[10];
  const float* b1  = (const float*)d_in[11];
  const float* W2  = (const float*)d_in[12];
  const float* as2 = (const float*)d_in[13];
  const float* ad2 = (const float*)d_in[14];
  const float* b2  = (const float*)d_in[15];
  const float* mW1 = (const float*)d_in[16];
  const float* mb1 = (const float*)d_in[17];
  const float* mW2 = (const float*)d_in[18];
  const float* mb2 = (const float*)d_in[19];
  const float* rW  = (const float*)d_in[20];
  const float* rb  = (const float*)d_in[21];
  float* out = (float*)d_out;

  const int N = in_sizes[2];       // 50000
  const int E = in_sizes[1] / 2;   // 800000
  const int TOT = E + N;           // edges incl self loops
  const int G = out_size;          // 64

  // workspace carve-up
  char* p = (char*)d_ws;
  auto alloc = [&](size_t bytes) {
    void* r = (void*)p;
    p += (bytes + 255) & ~(size_t)255;
    return r;
  };
  float* hA      = (float*)alloc((size_t)(N + 16) * 128 * 4);
  float* hWbuf   = (float*)alloc((size_t)(N + 16) * 256 * 4);
  float* hB      = (float*)alloc((size_t)(N + 16) * 64 * 4);
  float* a_srcv  = (float*)alloc((size_t)N * 4 * 4);
  float* a_dstv  = (float*)alloc((size_t)N * 4 * 4);
  int*   deg     = (int*)alloc((size_t)N * 4);
  int*   row_ptr = (int*)alloc((size_t)(N + 1) * 4);
  int*   bsum    = (int*)alloc(256 * 4);
  int*   csr     = (int*)alloc((size_t)TOT * 4);
  float* pooled  = (float*)alloc((size_t)G * 64 * 4);
  int*   gstart  = (int*)alloc((size_t)(G + 1) * 4);

  int gTOT = (TOT + TPB - 1) / TPB;
  int gN   = (N + TPB - 1) / TPB;
  int B    = gN;  // scan blocks (<=256 for N<=65536)

  // ---- CSR build (per call; ws is re-poisoned each launch) ----
  hipMemsetAsync(deg, 0, (size_t)N * 4, stream);
  edge_hist_k<<<gTOT, TPB, 0, stream>>>(ei, deg, E, N);
  scan_block_k<<<B, TPB, 0, stream>>>(deg, row_ptr, bsum, N);
  scan_bsum_k<<<1, TPB, 0, stream>>>(bsum, B);
  scan_add_k<<<gN, TPB, 0, stream>>>(row_ptr, bsum, N);
  hipMemsetAsync(deg, 0, (size_t)N * 4, stream);  // reuse as cursor
  edge_scatter_k<<<gTOT, TPB, 0, stream>>>(ei, row_ptr, deg, csr, E, N);

  // ---- group bounds for pooling (batch sorted => contiguous groups) ----
  group_bounds_k<<<gN, TPB, 0, stream>>>(batch, gstart, G, N);

  // ---- embedding gather ----
  gather_emb_k<<<(N * 128 + TPB - 1) / TPB, TPB, 0, stream>>>(x, emb, hA, N);

  int gGemm = (N + 15) / 16;
  int gCoef = (N * 4 + TPB - 1) / TPB;

  // ---- layer 0 ----
  gemm_hw_k<128><<<gGemm, TPB, 0, stream>>>(hA, W0, hWbuf, N);
  attn_coef_k<<<gCoef, TPB, 0, stream>>>(hWbuf, as0, ad0, a_srcv, a_dstv, N);
  gat_agg_k<<<N, TPB, 0, stream>>>(hWbuf, a_srcv, a_dstv, row_ptr, csr, b0, hB, N);
  // ---- layer 1 ----
  gemm_hw_k<64><<<gGemm, TPB, 0, stream>>>(hB, W1, hWbuf, N);
  attn_coef_k<<<gCoef, TPB, 0, stream>>>(hWbuf, as1, ad1, a_srcv, a_dstv, N);
  gat_agg_k<<<N, TPB, 0, stream>>>(hWbuf, a_srcv, a_dstv, row_ptr, csr, b1, hA, N);
  // ---- layer 2 ----
  gemm_hw_k<64><<<gGemm, TPB, 0, stream>>>(hA, W2, hWbuf, N);
  attn_coef_k<<<gCoef, TPB, 0, stream>>>(hWbuf, as2, ad2, a_srcv, a_dstv, N);
  gat_agg_k<<<N, TPB, 0, stream>>>(hWbuf, a_srcv, a_dstv, row_ptr, csr, b2, hB, N);

  // ---- pooling + readout (atomic-free) ----
  pool_group_k<<<G, TPB, 0, stream>>>(hB, gstart, pooled);
  readout_k<<<G, 64, 0, stream>>>(pooled, mW1, mb1, mW2, mb2, rW, rb, out);
}